// Round 4
// baseline (208.228 us; speedup 1.0000x reference)
//
#include <hip/hip_runtime.h>

#define N_PTS 65536
#define NSS 16
#define C 64

typedef __attribute__((ext_vector_type(8))) short short8;
typedef __attribute__((ext_vector_type(4))) float f32x4;

__device__ __forceinline__ unsigned short f2bf(float v) {
  unsigned int u = __float_as_uint(v);
  u += 0x7fffu + ((u >> 16) & 1u);  // RNE
  return (unsigned short)(u >> 16);
}
__device__ __forceinline__ float bflo(unsigned int u) { return __uint_as_float(u << 16); }
__device__ __forceinline__ float bfhi(unsigned int u) { return __uint_as_float(u & 0xffff0000u); }

// 16x16x16 morton cell id of a point (p in [0,10])
__device__ __forceinline__ int cell_of(float px, float py, float pz) {
  const int cx = min(15, max(0, (int)(px * 1.6f)));
  const int cy = min(15, max(0, (int)(py * 1.6f)));
  const int cz = min(15, max(0, (int)(pz * 1.6f)));
  int m = 0;
#pragma unroll
  for (int b = 0; b < 4; ++b)
    m |= (((cx >> b) & 1) << (3 * b + 2)) | (((cy >> b) & 1) << (3 * b + 1)) |
         (((cz >> b) & 1) << (3 * b));
  return m;
}

// ---------------- init: stats=0, wt (QKV weights bf16 transposed), wtq/tb (T-fold), hist ----------------
__global__ __launch_bounds__(256) void init_kernel(
    const float* __restrict__ Wq, const float* __restrict__ Wk, const float* __restrict__ Wv,
    const float* __restrict__ Wp2, const float* __restrict__ bp2, const float* __restrict__ bq,
    const float* __restrict__ p,
    float* __restrict__ stats, unsigned short* __restrict__ wt,
    unsigned short* __restrict__ wtq, float* __restrict__ tb, int* __restrict__ hist) {
  const int t = blockIdx.x * 256 + threadIdx.x;
  if (t < 9) stats[t] = 0.f;
  if (t < 192 * 64) {
    const int k = t / 192, ng = t % 192;
    const int mat = ng >> 6, n = ng & 63;
    const float* W = mat == 0 ? Wq : (mat == 1 ? Wk : Wv);
    wt[ng * 64 + k] = f2bf(W[k * 64 + n]);
  }
  if (t < 1024) {  // wtq[row][k] = sum_c Wq[k][c] * B2[row][c], rows 4..15 zero
    const int row = t >> 6, k = t & 63;
    float val = 0.f;
    if (row < 4) {
      const float* B2 = (row == 3) ? bp2 : (Wp2 + row * 64);
      for (int c2 = 0; c2 < 64; ++c2) val += Wq[k * 64 + c2] * B2[c2];
    }
    wtq[t] = f2bf(val);
  }
  if (t >= 1024 && t < 1028) {
    const int n2 = t - 1024;
    const float* B2 = (n2 == 3) ? bp2 : (Wp2 + n2 * 64);
    float val = 0.f;
    for (int c2 = 0; c2 < 64; ++c2) val += bq[c2] * B2[c2];
    tb[n2] = val;
  }
  if (t < N_PTS) {
    atomicAdd(&hist[cell_of(p[t * 3 + 0], p[t * 3 + 1], p[t * 3 + 2])], 1);
  }
}

// ---------------- scan: exclusive prefix over 4096 cell counts ----------------
__global__ __launch_bounds__(256) void scan_kernel(const int* __restrict__ hist,
                                                   int* __restrict__ offs) {
  __shared__ int part[256];
  const int t = threadIdx.x;
  int sum = 0;
#pragma unroll
  for (int i = 0; i < 16; ++i) sum += hist[t * 16 + i];
  part[t] = sum;
  __syncthreads();
  if (t == 0) {
    int run = 0;
    for (int i = 0; i < 256; ++i) { const int v = part[i]; part[i] = run; run += v; }
  }
  __syncthreads();
  int run = part[t];
  for (int i = 0; i < 16; ++i) { offs[t * 16 + i] = run; run += hist[t * 16 + i]; }
}

// ---------------- scatter: perm[sorted_pos] = original index ----------------
__global__ __launch_bounds__(256) void scatter_kernel(const float* __restrict__ p,
                                                      int* __restrict__ offs,
                                                      int* __restrict__ perm) {
  const int t = blockIdx.x * 256 + threadIdx.x;
  const int cidx = cell_of(p[t * 3 + 0], p[t * 3 + 1], p[t * 3 + 2]);
  const int pos = atomicAdd(&offs[cidx], 1);
  perm[pos] = t;
}

// ---------------- QKV via MFMA + T-precompute + fused stats ----------------
// kvq[N][192] bf16 (Q|K|V rows); tq[N][4] fp32
__global__ __launch_bounds__(256) void qkv_kernel(
    const float* __restrict__ x, const unsigned short* __restrict__ wt,
    const unsigned short* __restrict__ wtq, const float* __restrict__ tb,
    const float* __restrict__ bq, const float* __restrict__ bk, const float* __restrict__ bv,
    const float* __restrict__ p, const int* __restrict__ idx,
    unsigned short* __restrict__ kvq, float* __restrict__ tq, float* __restrict__ stats) {
  __shared__ __align__(16) unsigned short xs[64][72];
  __shared__ __align__(16) unsigned short kvs[64][192];  // matches global layout
  const int t = threadIdx.x;
  const int p0 = blockIdx.x * 64;
  const float4* x4 = (const float4*)x;
#pragma unroll
  for (int j = 0; j < 4; ++j) {
    const int id = j * 256 + t;
    const int row = id >> 4, cg = id & 15;
    const float4 v = x4[(p0 + row) * 16 + cg];
    ushort4 h4;
    h4.x = f2bf(v.x); h4.y = f2bf(v.y); h4.z = f2bf(v.z); h4.w = f2bf(v.w);
    *(ushort4*)&xs[row][cg * 4] = h4;
  }
  __syncthreads();

  const int lane = t & 63, wave = t >> 6;
  const int quad = lane >> 4, lr = lane & 15;
  const int mrow = wave * 16 + lr;
  const short8 a0 = *(const short8*)&xs[mrow][quad * 8];
  const short8 a1 = *(const short8*)&xs[mrow][quad * 8 + 32];
#pragma unroll
  for (int nt = 0; nt < 12; ++nt) {
    const unsigned short* bpr = wt + (nt * 16 + lr) * 64 + quad * 8;
    const short8 b0 = *(const short8*)bpr;
    const short8 b1 = *(const short8*)(bpr + 32);
    f32x4 acc = {0.f, 0.f, 0.f, 0.f};
    acc = __builtin_amdgcn_mfma_f32_16x16x32_bf16(a0, b0, acc, 0, 0, 0);
    acc = __builtin_amdgcn_mfma_f32_16x16x32_bf16(a1, b1, acc, 0, 0, 0);
    const int mat = nt >> 2;
    const int c = (nt & 3) * 16 + lr;
    const float bias = (mat == 0 ? bq : (mat == 1 ? bk : bv))[c];
#pragma unroll
    for (int r = 0; r < 4; ++r) {
      const int row = wave * 16 + quad * 4 + r;
      kvs[row][mat * 64 + c] = f2bf(acc[r] + bias);
    }
  }
  {  // T = q . [Wp2 rows | bp2]
    const unsigned short* bpr = wtq + lr * 64 + quad * 8;
    const short8 b0 = *(const short8*)bpr;
    const short8 b1 = *(const short8*)(bpr + 32);
    f32x4 acc = {0.f, 0.f, 0.f, 0.f};
    acc = __builtin_amdgcn_mfma_f32_16x16x32_bf16(a0, b0, acc, 0, 0, 0);
    acc = __builtin_amdgcn_mfma_f32_16x16x32_bf16(a1, b1, acc, 0, 0, 0);
    if (lr < 4) {
      const float tbv = tb[lr];
#pragma unroll
      for (int r = 0; r < 4; ++r) {
        const int pt = p0 + wave * 16 + quad * 4 + r;
        tq[pt * 4 + lr] = acc[r] + tbv;
      }
    }
  }
  __syncthreads();
  // coalesced kvq store: 64 rows x 384 B contiguous = 1536 uint4
  const uint4* kvs4 = (const uint4*)&kvs[0][0];
  uint4* dst = (uint4*)(kvq + (size_t)p0 * 192);
#pragma unroll
  for (int j = 0; j < 6; ++j) dst[j * 256 + t] = kvs4[j * 256 + t];

  // ---- fused stats: moments of p_r ----
  const int tid = blockIdx.x * 256 + t;
  float s0 = 0, s1 = 0, s2 = 0, s00 = 0, s01 = 0, s02 = 0, s11 = 0, s12 = 0, s22 = 0;
  for (int s = tid; s < N_PTS * NSS; s += 262144) {
    const int n = s >> 4;
    const int j = idx[s];
    const float dx = p[j * 3 + 0] - p[n * 3 + 0];
    const float dy = p[j * 3 + 1] - p[n * 3 + 1];
    const float dz = p[j * 3 + 2] - p[n * 3 + 2];
    s0 += dx; s1 += dy; s2 += dz;
    s00 += dx * dx; s01 += dx * dy; s02 += dx * dz;
    s11 += dy * dy; s12 += dy * dz; s22 += dz * dz;
  }
#pragma unroll
  for (int m = 1; m < 64; m <<= 1) {
    s0 += __shfl_xor(s0, m, 64);  s1 += __shfl_xor(s1, m, 64);  s2 += __shfl_xor(s2, m, 64);
    s00 += __shfl_xor(s00, m, 64); s01 += __shfl_xor(s01, m, 64); s02 += __shfl_xor(s02, m, 64);
    s11 += __shfl_xor(s11, m, 64); s12 += __shfl_xor(s12, m, 64); s22 += __shfl_xor(s22, m, 64);
  }
  __shared__ float part[4][9];
  if (lane == 0) {
    part[wave][0] = s0;  part[wave][1] = s1;  part[wave][2] = s2;
    part[wave][3] = s00; part[wave][4] = s01; part[wave][5] = s02;
    part[wave][6] = s11; part[wave][7] = s12; part[wave][8] = s22;
  }
  __syncthreads();
  if (t < 9) {
    atomicAdd(&stats[t], part[0][t] + part[1][t] + part[2][t] + part[3][t]);
  }
}

// ---------------- cross-lane helpers ----------------
template <int CTRL>
__device__ __forceinline__ float dppmv(float x) {
  return __int_as_float(__builtin_amdgcn_update_dpp(
      __float_as_int(x), __float_as_int(x), CTRL, 0xF, 0xF, true));
}
__device__ __forceinline__ float red16_add(float x) {
  x += dppmv<0xB1>(x);
  x += dppmv<0x4E>(x);
  x += __shfl_xor(x, 4, 64);
  x += __shfl_xor(x, 8, 64);
  return x;
}
__device__ __forceinline__ float red16_max(float x) {
  x = fmaxf(x, dppmv<0xB1>(x));
  x = fmaxf(x, dppmv<0x4E>(x));
  x = fmaxf(x, __shfl_xor(x, 4, 64));
  x = fmaxf(x, __shfl_xor(x, 8, 64));
  return x;
}
__device__ __forceinline__ float red8_add(float x) {
  x += dppmv<0xB1>(x);
  x += dppmv<0x4E>(x);
  x += __shfl_xor(x, 4, 64);
  return x;
}

// ---------------- attention: one wave per (sorted) point ----------------
// s = lane&15 (neighbor), MFMA computes all 16 q.k scores; V in slice/rlo layout.
__global__ __launch_bounds__(256, 4) void attn_kernel(
    const float* __restrict__ p, const int* __restrict__ idx,
    const unsigned short* __restrict__ kvq, const float* __restrict__ tq,
    const int* __restrict__ perm, const float* __restrict__ stats,
    const float* __restrict__ Wp1, const float* __restrict__ bp1,
    const float* __restrict__ gamma, const float* __restrict__ beta,
    const float* __restrict__ Wp2, const float* __restrict__ bp2,
    float* __restrict__ out) {
  const int lane = threadIdx.x & 63;
  const int wave = threadIdx.x >> 6;
  const int b = blockIdx.x;
  // XCD swizzle: XCD k sweeps one contiguous spatial chunk of the sorted order
  const int sb = (b & 7) * (N_PTS / 4 / 8) + (b >> 3);
  const int n = perm[sb * 4 + wave];
  const int quad = lane >> 4, s = lane & 15;
  const int slice = lane >> 3, rlo = lane & 7;

  const int jall = idx[n * NSS + s];
  // MFMA fragments: A = broadcast q row (bf16), B = 16 gathered K rows
  const short8 a0 = *(const short8*)(kvq + (size_t)n * 192 + quad * 8);
  const short8 a1 = *(const short8*)(kvq + (size_t)n * 192 + quad * 8 + 32);
  const short8 bk0 = *(const short8*)(kvq + (size_t)jall * 192 + 64 + quad * 8);
  const short8 bk1 = *(const short8*)(kvq + (size_t)jall * 192 + 64 + quad * 8 + 32);
  // V gathers (slice/rlo layout)
  const int jb0 = __shfl(jall, rlo, 64);
  const int jb1 = __shfl(jall, rlo | 8, 64);
  const uint4 vr0 = *(const uint4*)(kvq + (size_t)jb0 * 192 + 128 + slice * 8);
  const uint4 vr1 = *(const uint4*)(kvq + (size_t)jb1 * 192 + 128 + slice * 8);
  const float4 t4 = ((const float4*)tq)[n];
  const float pjx = p[jall * 3 + 0], pjy = p[jall * 3 + 1], pjz = p[jall * 3 + 2];
  const float pnx = p[n * 3 + 0], pny = p[n * 3 + 1], pnz = p[n * 3 + 2];

  const float4* w24 = (const float4*)Wp2;
  const float4 w20a = w24[slice * 2],      w20b = w24[slice * 2 + 1];
  const float4 w21a = w24[16 + slice * 2], w21b = w24[16 + slice * 2 + 1];
  const float4 w22a = w24[32 + slice * 2], w22b = w24[32 + slice * 2 + 1];
  const float4* bp24 = (const float4*)bp2;
  const float4 b2a = bp24[slice * 2], b2b = bp24[slice * 2 + 1];

  // BN fold (wave-uniform)
  const float invM = 1.0f / (float)(N_PTS * NSS);
  const float m0 = stats[0] * invM, m1 = stats[1] * invM, m2 = stats[2] * invM;
  const float cv00 = stats[3] * invM - m0 * m0, cv01 = stats[4] * invM - m0 * m1;
  const float cv02 = stats[5] * invM - m0 * m2, cv11 = stats[6] * invM - m1 * m1;
  const float cv12 = stats[7] * invM - m1 * m2, cv22 = stats[8] * invM - m2 * m2;
  float e[12];
#pragma unroll
  for (int tt = 0; tt < 3; ++tt) {
    const float w0 = Wp1[0 * 3 + tt], w1 = Wp1[1 * 3 + tt], w2 = Wp1[2 * 3 + tt];
    const float mh = w0 * m0 + w1 * m1 + w2 * m2 + bp1[tt];
    const float var = w0 * w0 * cv00 + w1 * w1 * cv11 + w2 * w2 * cv22 +
                      2.f * (w0 * w1 * cv01 + w0 * w2 * cv02 + w1 * w2 * cv12);
    const float sc = gamma[tt] * rsqrtf(var + 1e-5f);
    e[tt] = w0 * sc; e[3 + tt] = w1 * sc; e[6 + tt] = w2 * sc;
    e[9 + tt] = (bp1[tt] - mh) * sc + beta[tt];
  }

  // K scores via MFMA: lane gets score for its s in acc[0]
  f32x4 acc = {0.f, 0.f, 0.f, 0.f};
  acc = __builtin_amdgcn_mfma_f32_16x16x32_bf16(a0, bk0, acc, 0, 0, 0);
  acc = __builtin_amdgcn_mfma_f32_16x16x32_bf16(a1, bk1, acc, 0, 0, 0);
  const float S = acc[0];

  // h for own s
  const float dx = pjx - pnx, dy = pjy - pny, dz = pjz - pnz;
  const float h0 = fmaxf(fmaf(dx, e[0], fmaf(dy, e[3], fmaf(dz, e[6], e[9]))), 0.f);
  const float h1 = fmaxf(fmaf(dx, e[1], fmaf(dy, e[4], fmaf(dz, e[7], e[10]))), 0.f);
  const float h2 = fmaxf(fmaf(dx, e[2], fmaf(dy, e[5], fmaf(dz, e[8], e[11]))), 0.f);

  const float a = (S + fmaf(h0, t4.x, fmaf(h1, t4.y, fmaf(h2, t4.z, t4.w)))) * 0.125f;
  const float mx = red16_max(a);
  const float ex = __expf(a - mx);
  const float den = red16_add(ex);
  const float w = ex / den;

  const float H0 = red16_add(w * h0);
  const float H1 = red16_add(w * h1);
  const float H2 = red16_add(w * h2);

  // V phase
  const float wb0 = __shfl(w, rlo, 64);
  const float wb1 = __shfl(w, rlo | 8, 64);
  const unsigned int v0c[4] = {vr0.x, vr0.y, vr0.z, vr0.w};
  const unsigned int v1c[4] = {vr1.x, vr1.y, vr1.z, vr1.w};
  float o[8];
#pragma unroll
  for (int q2 = 0; q2 < 4; ++q2) {
    o[2 * q2]     = fmaf(wb0, bflo(v0c[q2]), wb1 * bflo(v1c[q2]));
    o[2 * q2 + 1] = fmaf(wb0, bfhi(v0c[q2]), wb1 * bfhi(v1c[q2]));
  }
#pragma unroll
  for (int j = 0; j < 8; ++j) o[j] = red8_add(o[j]);

  const float w20f[8] = {w20a.x, w20a.y, w20a.z, w20a.w, w20b.x, w20b.y, w20b.z, w20b.w};
  const float w21f[8] = {w21a.x, w21a.y, w21a.z, w21a.w, w21b.x, w21b.y, w21b.z, w21b.w};
  const float w22f[8] = {w22a.x, w22a.y, w22a.z, w22a.w, w22b.x, w22b.y, w22b.z, w22b.w};
  const float b2f[8]  = {b2a.x, b2a.y, b2a.z, b2a.w, b2b.x, b2b.y, b2b.z, b2b.w};
#pragma unroll
  for (int j = 0; j < 8; ++j)
    o[j] += fmaf(H0, w20f[j], fmaf(H1, w21f[j], fmaf(H2, w22f[j], b2f[j])));

  if (rlo == 0) {
    float4 oa = {o[0], o[1], o[2], o[3]};
    float4 ob = {o[4], o[5], o[6], o[7]};
    float4* o4 = (float4*)out;
    o4[n * 16 + slice * 2] = oa;
    o4[n * 16 + slice * 2 + 1] = ob;
  }
}

extern "C" void kernel_launch(void* const* d_in, const int* in_sizes, int n_in,
                              void* d_out, int out_size, void* d_ws, size_t ws_size,
                              hipStream_t stream) {
  const float* p     = (const float*)d_in[0];
  const float* x     = (const float*)d_in[1];
  const int*   idx   = (const int*)d_in[2];
  const float* Wq    = (const float*)d_in[3];
  const float* bq    = (const float*)d_in[4];
  const float* Wk    = (const float*)d_in[5];
  const float* bk    = (const float*)d_in[6];
  const float* Wv    = (const float*)d_in[7];
  const float* bv    = (const float*)d_in[8];
  const float* Wp1   = (const float*)d_in[9];
  const float* bp1   = (const float*)d_in[10];
  const float* gamma = (const float*)d_in[11];
  const float* beta  = (const float*)d_in[12];
  const float* Wp2   = (const float*)d_in[13];
  const float* bp2   = (const float*)d_in[14];
  float* out = (float*)d_out;

  char* w = (char*)d_ws;
  float* stats        = (float*)w;                          // 36 B
  float* tb           = (float*)(w + 64);                   // 16 B
  unsigned short* wt  = (unsigned short*)(w + 256);         // 24576 B
  unsigned short* wtq = (unsigned short*)(w + 25088);       // 2048 B
  int* hist           = (int*)(w + 32768);                  // 16384 B
  int* offs           = (int*)(w + 49152);                  // 16384 B
  int* perm           = (int*)(w + 65536);                  // 262144 B
  unsigned short* kvq = (unsigned short*)(w + 327680);      // 25165824 B
  float* tq           = (float*)(w + 25493504);             // 1048576 B

  hipMemsetAsync(hist, 0, 4096 * sizeof(int), stream);
  init_kernel<<<256, 256, 0, stream>>>(Wq, Wk, Wv, Wp2, bp2, bq, p, stats, wt, wtq, tb, hist);
  scan_kernel<<<1, 256, 0, stream>>>(hist, offs);
  scatter_kernel<<<256, 256, 0, stream>>>(p, offs, perm);
  qkv_kernel<<<N_PTS / 64, 256, 0, stream>>>(x, wt, wtq, tb, bq, bk, bv, p, idx, kvq, tq, stats);
  attn_kernel<<<N_PTS / 4, 256, 0, stream>>>(p, idx, kvq, tq, perm, stats, Wp1, bp1, gamma,
                                             beta, Wp2, bp2, out);
}

// Round 5
// 182.596 us; speedup vs baseline: 1.1404x; 1.1404x over previous
//
#include <hip/hip_runtime.h>

#define N_PTS 65536
#define NSS 16
#define C 64

typedef __attribute__((ext_vector_type(8))) short short8;
typedef __attribute__((ext_vector_type(4))) float f32x4;

__device__ __forceinline__ unsigned short f2bf(float v) {
  unsigned int u = __float_as_uint(v);
  u += 0x7fffu + ((u >> 16) & 1u);  // RNE
  return (unsigned short)(u >> 16);
}
__device__ __forceinline__ float bflo(unsigned int u) { return __uint_as_float(u << 16); }
__device__ __forceinline__ float bfhi(unsigned int u) { return __uint_as_float(u & 0xffff0000u); }

// 16x16x16 morton cell id of a point (p in [0,10])
__device__ __forceinline__ int cell_of(float px, float py, float pz) {
  const int cx = min(15, max(0, (int)(px * 1.6f)));
  const int cy = min(15, max(0, (int)(py * 1.6f)));
  const int cz = min(15, max(0, (int)(pz * 1.6f)));
  int m = 0;
#pragma unroll
  for (int b = 0; b < 4; ++b)
    m |= (((cx >> b) & 1) << (3 * b + 2)) | (((cy >> b) & 1) << (3 * b + 1)) |
         (((cz >> b) & 1) << (3 * b));
  return m;
}

// ---------------- init: stats=0, wt (QKV weights bf16 transposed), wtq/tb (T-fold), hist ----------------
__global__ __launch_bounds__(256) void init_kernel(
    const float* __restrict__ Wq, const float* __restrict__ Wk, const float* __restrict__ Wv,
    const float* __restrict__ Wp2, const float* __restrict__ bp2, const float* __restrict__ bq,
    const float* __restrict__ p,
    float* __restrict__ stats, unsigned short* __restrict__ wt,
    unsigned short* __restrict__ wtq, float* __restrict__ tb, int* __restrict__ hist) {
  const int t = blockIdx.x * 256 + threadIdx.x;
  if (t < 9) stats[t] = 0.f;
  if (t < 192 * 64) {
    const int k = t / 192, ng = t % 192;
    const int mat = ng >> 6, n = ng & 63;
    const float* W = mat == 0 ? Wq : (mat == 1 ? Wk : Wv);
    wt[ng * 64 + k] = f2bf(W[k * 64 + n]);
  }
  if (t < 1024) {  // wtq[row][k] = sum_c Wq[k][c] * B2[row][c], rows 4..15 zero
    const int row = t >> 6, k = t & 63;
    float val = 0.f;
    if (row < 4) {
      const float* B2 = (row == 3) ? bp2 : (Wp2 + row * 64);
      for (int c2 = 0; c2 < 64; ++c2) val += Wq[k * 64 + c2] * B2[c2];
    }
    wtq[t] = f2bf(val);
  }
  if (t >= 1024 && t < 1028) {
    const int n2 = t - 1024;
    const float* B2 = (n2 == 3) ? bp2 : (Wp2 + n2 * 64);
    float val = 0.f;
    for (int c2 = 0; c2 < 64; ++c2) val += bq[c2] * B2[c2];
    tb[n2] = val;
  }
  if (t < N_PTS) {
    atomicAdd(&hist[cell_of(p[t * 3 + 0], p[t * 3 + 1], p[t * 3 + 2])], 1);
  }
}

// ---------------- QKV via MFMA + T-precompute + fused stats ----------------
// kvq[N][192] bf16 (Q|K|V rows); tq[N][4] fp32
__global__ __launch_bounds__(256) void qkv_kernel(
    const float* __restrict__ x, const unsigned short* __restrict__ wt,
    const unsigned short* __restrict__ wtq, const float* __restrict__ tb,
    const float* __restrict__ bq, const float* __restrict__ bk, const float* __restrict__ bv,
    const float* __restrict__ p, const int* __restrict__ idx,
    unsigned short* __restrict__ kvq, float* __restrict__ tq, float* __restrict__ stats) {
  __shared__ __align__(16) unsigned short xs[64][72];
  __shared__ __align__(16) unsigned short kvs[64][192];  // matches global layout
  const int t = threadIdx.x;
  const int p0 = blockIdx.x * 64;
  const float4* x4 = (const float4*)x;
#pragma unroll
  for (int j = 0; j < 4; ++j) {
    const int id = j * 256 + t;
    const int row = id >> 4, cg = id & 15;
    const float4 v = x4[(p0 + row) * 16 + cg];
    ushort4 h4;
    h4.x = f2bf(v.x); h4.y = f2bf(v.y); h4.z = f2bf(v.z); h4.w = f2bf(v.w);
    *(ushort4*)&xs[row][cg * 4] = h4;
  }
  __syncthreads();

  const int lane = t & 63, wave = t >> 6;
  const int quad = lane >> 4, lr = lane & 15;
  const int mrow = wave * 16 + lr;
  const short8 a0 = *(const short8*)&xs[mrow][quad * 8];
  const short8 a1 = *(const short8*)&xs[mrow][quad * 8 + 32];
#pragma unroll
  for (int nt = 0; nt < 12; ++nt) {
    const unsigned short* bpr = wt + (nt * 16 + lr) * 64 + quad * 8;
    const short8 b0 = *(const short8*)bpr;
    const short8 b1 = *(const short8*)(bpr + 32);
    f32x4 acc = {0.f, 0.f, 0.f, 0.f};
    acc = __builtin_amdgcn_mfma_f32_16x16x32_bf16(a0, b0, acc, 0, 0, 0);
    acc = __builtin_amdgcn_mfma_f32_16x16x32_bf16(a1, b1, acc, 0, 0, 0);
    const int mat = nt >> 2;
    const int c = (nt & 3) * 16 + lr;
    const float bias = (mat == 0 ? bq : (mat == 1 ? bk : bv))[c];
#pragma unroll
    for (int r = 0; r < 4; ++r) {
      const int row = wave * 16 + quad * 4 + r;
      kvs[row][mat * 64 + c] = f2bf(acc[r] + bias);
    }
  }
  {  // T = q . [Wp2 rows | bp2]
    const unsigned short* bpr = wtq + lr * 64 + quad * 8;
    const short8 b0 = *(const short8*)bpr;
    const short8 b1 = *(const short8*)(bpr + 32);
    f32x4 acc = {0.f, 0.f, 0.f, 0.f};
    acc = __builtin_amdgcn_mfma_f32_16x16x32_bf16(a0, b0, acc, 0, 0, 0);
    acc = __builtin_amdgcn_mfma_f32_16x16x32_bf16(a1, b1, acc, 0, 0, 0);
    if (lr < 4) {
      const float tbv = tb[lr];
#pragma unroll
      for (int r = 0; r < 4; ++r) {
        const int pt = p0 + wave * 16 + quad * 4 + r;
        tq[pt * 4 + lr] = acc[r] + tbv;
      }
    }
  }
  __syncthreads();
  // coalesced kvq store: 64 rows x 384 B contiguous = 1536 uint4
  const uint4* kvs4 = (const uint4*)&kvs[0][0];
  uint4* dst = (uint4*)(kvq + (size_t)p0 * 192);
#pragma unroll
  for (int j = 0; j < 6; ++j) dst[j * 256 + t] = kvs4[j * 256 + t];

  // ---- fused stats: moments of p_r ----
  const int tid = blockIdx.x * 256 + t;
  float s0 = 0, s1 = 0, s2 = 0, s00 = 0, s01 = 0, s02 = 0, s11 = 0, s12 = 0, s22 = 0;
  for (int s = tid; s < N_PTS * NSS; s += 262144) {
    const int n = s >> 4;
    const int j = idx[s];
    const float dx = p[j * 3 + 0] - p[n * 3 + 0];
    const float dy = p[j * 3 + 1] - p[n * 3 + 1];
    const float dz = p[j * 3 + 2] - p[n * 3 + 2];
    s0 += dx; s1 += dy; s2 += dz;
    s00 += dx * dx; s01 += dx * dy; s02 += dx * dz;
    s11 += dy * dy; s12 += dy * dz; s22 += dz * dz;
  }
#pragma unroll
  for (int m = 1; m < 64; m <<= 1) {
    s0 += __shfl_xor(s0, m, 64);  s1 += __shfl_xor(s1, m, 64);  s2 += __shfl_xor(s2, m, 64);
    s00 += __shfl_xor(s00, m, 64); s01 += __shfl_xor(s01, m, 64); s02 += __shfl_xor(s02, m, 64);
    s11 += __shfl_xor(s11, m, 64); s12 += __shfl_xor(s12, m, 64); s22 += __shfl_xor(s22, m, 64);
  }
  __shared__ float part[4][9];
  if (lane == 0) {
    part[wave][0] = s0;  part[wave][1] = s1;  part[wave][2] = s2;
    part[wave][3] = s00; part[wave][4] = s01; part[wave][5] = s02;
    part[wave][6] = s11; part[wave][7] = s12; part[wave][8] = s22;
  }
  __syncthreads();
  if (t < 9) {
    atomicAdd(&stats[t], part[0][t] + part[1][t] + part[2][t] + part[3][t]);
  }
}

// ---------------- scan (parallel) + BN fold into ebn[12] ----------------
__global__ __launch_bounds__(256) void scan_kernel(
    const int* __restrict__ hist, int* __restrict__ offs,
    const float* __restrict__ stats,
    const float* __restrict__ Wp1, const float* __restrict__ bp1,
    const float* __restrict__ gamma, const float* __restrict__ beta,
    float* __restrict__ ebn) {
  const int t = threadIdx.x;
  const int lane = t & 63, wv = t >> 6;
  int loc[16];
  int sum = 0;
#pragma unroll
  for (int i = 0; i < 16; ++i) { loc[i] = hist[t * 16 + i]; sum += loc[i]; }
  int incl = sum;
#pragma unroll
  for (int off = 1; off < 64; off <<= 1) {
    const int v = __shfl_up(incl, off, 64);
    if (lane >= off) incl += v;
  }
  __shared__ int wtot[4];
  if (lane == 63) wtot[wv] = incl;
  __syncthreads();
  int wbase = 0;
#pragma unroll
  for (int i = 0; i < 4; ++i) wbase += (i < wv) ? wtot[i] : 0;
  int run = wbase + incl - sum;  // exclusive prefix
#pragma unroll
  for (int i = 0; i < 16; ++i) { offs[t * 16 + i] = run; run += loc[i]; }

  if (t == 0) {
    const float invM = 1.0f / (float)(N_PTS * NSS);
    const float m0 = stats[0] * invM, m1 = stats[1] * invM, m2 = stats[2] * invM;
    const float cv00 = stats[3] * invM - m0 * m0, cv01 = stats[4] * invM - m0 * m1;
    const float cv02 = stats[5] * invM - m0 * m2, cv11 = stats[6] * invM - m1 * m1;
    const float cv12 = stats[7] * invM - m1 * m2, cv22 = stats[8] * invM - m2 * m2;
#pragma unroll
    for (int tt = 0; tt < 3; ++tt) {
      const float w0 = Wp1[0 * 3 + tt], w1 = Wp1[1 * 3 + tt], w2 = Wp1[2 * 3 + tt];
      const float mh = w0 * m0 + w1 * m1 + w2 * m2 + bp1[tt];
      const float var = w0 * w0 * cv00 + w1 * w1 * cv11 + w2 * w2 * cv22 +
                        2.f * (w0 * w1 * cv01 + w0 * w2 * cv02 + w1 * w2 * cv12);
      const float sc = gamma[tt] * rsqrtf(var + 1e-5f);
      ebn[tt] = w0 * sc; ebn[3 + tt] = w1 * sc; ebn[6 + tt] = w2 * sc;
      ebn[9 + tt] = (bp1[tt] - mh) * sc + beta[tt];
    }
  }
}

// ---------------- scatter: perm[sorted_pos] = original index ----------------
__global__ __launch_bounds__(256) void scatter_kernel(const float* __restrict__ p,
                                                      int* __restrict__ offs,
                                                      int* __restrict__ perm) {
  const int t = blockIdx.x * 256 + threadIdx.x;
  const int cidx = cell_of(p[t * 3 + 0], p[t * 3 + 1], p[t * 3 + 2]);
  const int pos = atomicAdd(&offs[cidx], 1);
  perm[pos] = t;
}

// ---------------- cross-lane helpers (reductions confined to lane bits 0..3) ----------------
template <int CTRL>
__device__ __forceinline__ float dppmv(float x) {
  return __int_as_float(__builtin_amdgcn_update_dpp(
      __float_as_int(x), __float_as_int(x), CTRL, 0xF, 0xF, true));
}
__device__ __forceinline__ float red16_add(float x) {
  x += dppmv<0xB1>(x);
  x += dppmv<0x4E>(x);
  x += __shfl_xor(x, 4, 64);
  x += __shfl_xor(x, 8, 64);
  return x;
}
__device__ __forceinline__ float red16_max(float x) {
  x = fmaxf(x, dppmv<0xB1>(x));
  x = fmaxf(x, dppmv<0x4E>(x));
  x = fmaxf(x, __shfl_xor(x, 4, 64));
  x = fmaxf(x, __shfl_xor(x, 8, 64));
  return x;
}

// ---------------- attention: 4 points per wave, 16 lanes each ----------------
// group g = lane>>4 owns point n_g; within group, s = lane&15 = neighbor; channels 4s..4s+3.
__global__ __launch_bounds__(256, 4) void attn_kernel(
    const float* __restrict__ p, const int* __restrict__ idx,
    const unsigned short* __restrict__ kvq, const float* __restrict__ tq,
    const int* __restrict__ perm, const float* __restrict__ ebn,
    const float* __restrict__ Wp2, const float* __restrict__ bp2,
    float* __restrict__ out) {
  const int lane = threadIdx.x & 63;
  const int wave = threadIdx.x >> 6;
  const int b = blockIdx.x;
  // XCD swizzle over the sorted order: each XCD sweeps one contiguous spatial chunk
  const int sb = (b & 7) * 512 + (b >> 3);
  const int base = sb * 16 + wave * 4;
  const int quad = lane >> 4, lr = lane & 15;

  const int4 ng4 = *(const int4*)(perm + base);
  const int ng[4] = {ng4.x, ng4.y, ng4.z, ng4.w};
  const int nown = ng[quad];
  const int jall = idx[nown * NSS + lr];  // own (point, neighbor s=lr)

  // ---- scores via MFMA: 4 points, one MFMA pair each; lane keeps own group's ----
  float S = 0.f;
#pragma unroll
  for (int g = 0; g < 4; ++g) {
    const int jg = __shfl(jall, (g << 4) | lr, 64);
    const short8 a0 = *(const short8*)(kvq + (size_t)ng[g] * 192 + quad * 8);
    const short8 a1 = *(const short8*)(kvq + (size_t)ng[g] * 192 + quad * 8 + 32);
    const short8 k0 = *(const short8*)(kvq + (size_t)jg * 192 + 64 + quad * 8);
    const short8 k1 = *(const short8*)(kvq + (size_t)jg * 192 + 64 + quad * 8 + 32);
    f32x4 acc = {0.f, 0.f, 0.f, 0.f};
    acc = __builtin_amdgcn_mfma_f32_16x16x32_bf16(a0, k0, acc, 0, 0, 0);
    acc = __builtin_amdgcn_mfma_f32_16x16x32_bf16(a1, k1, acc, 0, 0, 0);
    S = (quad == g) ? acc[0] : S;  // D[row=quad*4][col=lr] = q_g . K_{j_{g,lr}}
  }

  // ---- h for own (g, s) ----
  float e[12];
#pragma unroll
  for (int i = 0; i < 12; ++i) e[i] = ebn[i];
  const float pnx = p[nown * 3 + 0], pny = p[nown * 3 + 1], pnz = p[nown * 3 + 2];
  const float dx = p[jall * 3 + 0] - pnx;
  const float dy = p[jall * 3 + 1] - pny;
  const float dz = p[jall * 3 + 2] - pnz;
  const float h0 = fmaxf(fmaf(dx, e[0], fmaf(dy, e[3], fmaf(dz, e[6], e[9]))), 0.f);
  const float h1 = fmaxf(fmaf(dx, e[1], fmaf(dy, e[4], fmaf(dz, e[7], e[10]))), 0.f);
  const float h2 = fmaxf(fmaf(dx, e[2], fmaf(dy, e[5], fmaf(dz, e[8], e[11]))), 0.f);

  const float4 t4 = ((const float4*)tq)[nown];
  const float a = (S + fmaf(h0, t4.x, fmaf(h1, t4.y, fmaf(h2, t4.z, t4.w)))) * 0.125f;

  // ---- softmax over s (lane bits 0..3) — one issue serves all 4 groups ----
  const float mx = red16_max(a);
  const float ex = __expf(a - mx);
  const float den = red16_add(ex);
  const float w = ex / den;

  const float H0 = red16_add(w * h0);
  const float H1 = red16_add(w * h1);
  const float H2 = red16_add(w * h2);

  // ---- V: lane owns channels 4*lr..4*lr+3 of its group's output ----
  float o0 = 0.f, o1 = 0.f, o2 = 0.f, o3 = 0.f;
#pragma unroll
  for (int s = 0; s < NSS; ++s) {
    const int jr = __shfl(jall, (lane & 48) | s, 64);
    const float ws = __shfl(w, (lane & 48) | s, 64);
    const uint2 v2 = *(const uint2*)(kvq + (size_t)jr * 192 + 128 + lr * 4);
    o0 = fmaf(ws, bflo(v2.x), o0);
    o1 = fmaf(ws, bfhi(v2.x), o1);
    o2 = fmaf(ws, bflo(v2.y), o2);
    o3 = fmaf(ws, bfhi(v2.y), o3);
  }

  // ---- epilogue: + H . Wp2[:, 4lr..] + bp2 ----
  const float4 w20 = ((const float4*)Wp2)[0 * 16 + lr];
  const float4 w21 = ((const float4*)Wp2)[16 + lr];
  const float4 w22 = ((const float4*)Wp2)[32 + lr];
  const float4 b2 = ((const float4*)bp2)[lr];
  o0 += fmaf(H0, w20.x, fmaf(H1, w21.x, fmaf(H2, w22.x, b2.x)));
  o1 += fmaf(H0, w20.y, fmaf(H1, w21.y, fmaf(H2, w22.y, b2.y)));
  o2 += fmaf(H0, w20.z, fmaf(H1, w21.z, fmaf(H2, w22.z, b2.z)));
  o3 += fmaf(H0, w20.w, fmaf(H1, w21.w, fmaf(H2, w22.w, b2.w)));
  const float4 res = {o0, o1, o2, o3};
  ((float4*)out)[nown * 16 + lr] = res;
}

extern "C" void kernel_launch(void* const* d_in, const int* in_sizes, int n_in,
                              void* d_out, int out_size, void* d_ws, size_t ws_size,
                              hipStream_t stream) {
  const float* p     = (const float*)d_in[0];
  const float* x     = (const float*)d_in[1];
  const int*   idx   = (const int*)d_in[2];
  const float* Wq    = (const float*)d_in[3];
  const float* bq    = (const float*)d_in[4];
  const float* Wk    = (const float*)d_in[5];
  const float* bk    = (const float*)d_in[6];
  const float* Wv    = (const float*)d_in[7];
  const float* bv    = (const float*)d_in[8];
  const float* Wp1   = (const float*)d_in[9];
  const float* bp1   = (const float*)d_in[10];
  const float* gamma = (const float*)d_in[11];
  const float* beta  = (const float*)d_in[12];
  const float* Wp2   = (const float*)d_in[13];
  const float* bp2   = (const float*)d_in[14];
  float* out = (float*)d_out;

  char* w = (char*)d_ws;
  float* stats        = (float*)w;                          // 36 B
  float* tb           = (float*)(w + 64);                   // 16 B
  float* ebn          = (float*)(w + 128);                  // 48 B
  unsigned short* wt  = (unsigned short*)(w + 256);         // 24576 B
  unsigned short* wtq = (unsigned short*)(w + 25088);       // 2048 B
  int* hist           = (int*)(w + 32768);                  // 16384 B
  int* offs           = (int*)(w + 49152);                  // 16384 B
  int* perm           = (int*)(w + 65536);                  // 262144 B
  unsigned short* kvq = (unsigned short*)(w + 327680);      // 25165824 B
  float* tq           = (float*)(w + 25493504);             // 1048576 B

  hipMemsetAsync(hist, 0, 4096 * sizeof(int), stream);
  init_kernel<<<256, 256, 0, stream>>>(Wq, Wk, Wv, Wp2, bp2, bq, p, stats, wt, wtq, tb, hist);
  qkv_kernel<<<N_PTS / 64, 256, 0, stream>>>(x, wt, wtq, tb, bq, bk, bv, p, idx, kvq, tq, stats);
  scan_kernel<<<1, 256, 0, stream>>>(hist, offs, stats, Wp1, bp1, gamma, beta, ebn);
  scatter_kernel<<<256, 256, 0, stream>>>(p, offs, perm);
  attn_kernel<<<N_PTS / 16, 256, 0, stream>>>(p, idx, kvq, tq, perm, ebn, Wp2, bp2, out);
}